// Round 3
// baseline (448.385 us; speedup 1.0000x reference)
//
#include <hip/hip_runtime.h>

#define NN 8192
#define EE 262144
#define IN_DIM 512
#define HD1 256
#define HD2 128

typedef __attribute__((ext_vector_type(8))) short bf16x8;
typedef __attribute__((ext_vector_type(4))) float f32x4;

__device__ inline unsigned short f2bf(float f) {
    unsigned int u = __builtin_bit_cast(unsigned int, f);
    u += 0x7fffu + ((u >> 16) & 1u);
    return (unsigned short)(u >> 16);
}
__device__ inline float bf2f(unsigned short u) {
    return __builtin_bit_cast(float, ((unsigned int)u) << 16);
}

// ---------------- graph preprocessing ----------------

__global__ void deg_kernel(const int* __restrict__ src, const int* __restrict__ dst,
                           int* __restrict__ deg_out, int* __restrict__ deg_in) {
    int e = blockIdx.x * blockDim.x + threadIdx.x;
    if (e < EE) {
        atomicAdd(&deg_out[src[e]], 1);
        atomicAdd(&deg_in[dst[e]], 1);
    }
}

// single block, 256 threads: exclusive scan of deg_in -> row_start, plus both norms
__global__ void scan_norm_kernel(const int* __restrict__ deg_in, const int* __restrict__ deg_out,
                                 int* __restrict__ row_start,
                                 float* __restrict__ norm_src, float* __restrict__ norm_dst) {
    __shared__ int sums[256];
    int t = threadIdx.x;
    int base = t * 32;
    int4 c[8];
#pragma unroll
    for (int i = 0; i < 8; i++) c[i] = ((const int4*)deg_in)[t * 8 + i];
    const int* ci = (const int*)c;
    int local[32];
    int s = 0;
#pragma unroll
    for (int i = 0; i < 32; i++) { local[i] = s; s += ci[i]; }
    sums[t] = s;
    __syncthreads();
    for (int off = 1; off < 256; off <<= 1) {
        int v = (t >= off) ? sums[t - off] : 0;
        __syncthreads();
        sums[t] += v;
        __syncthreads();
    }
    int coff = (t == 0) ? 0 : sums[t - 1];
#pragma unroll
    for (int i = 0; i < 32; i++) row_start[base + i] = coff + local[i];
    if (t == 255) row_start[NN] = sums[255];
    // norms (coalesced; deg_* are L2-resident, load by the SAME index we store to)
    for (int i = 0; i < 32; i++) {
        int idx = i * 256 + t;
        int dout = deg_out[idx]; if (dout < 1) dout = 1;
        int din  = deg_in[idx];  if (din  < 1) din  = 1;
        norm_src[idx] = rsqrtf((float)dout);
        norm_dst[idx] = rsqrtf((float)din);
    }
}

__global__ void fill_kernel(const int* __restrict__ src, const int* __restrict__ dst,
                            const int* __restrict__ row_start, int* __restrict__ cursor,
                            int* __restrict__ eidx) {
    int e = blockIdx.x * blockDim.x + threadIdx.x;
    if (e < EE) {
        int d = dst[e];
        int pos = atomicAdd(&cursor[d], 1);
        eidx[row_start[d] + pos] = src[e];
    }
}

// ---------------- fused casts: x -> bf16, W1^T -> bf16, W2^T -> bf16 ----------------

#define XN_QUADS (NN * IN_DIM / 4)   // 1048576
#define W1_ELEMS (IN_DIM * HD1)      // 131072
#define W2_ELEMS (HD1 * HD2)         // 32768

__global__ void cast_all_kernel(const float4* __restrict__ x, ushort4* __restrict__ xn,
                                const float* __restrict__ W1, unsigned short* __restrict__ w1t,
                                const float* __restrict__ W2, unsigned short* __restrict__ w2t) {
    int idx = blockIdx.x * 256 + threadIdx.x;
    if (idx < XN_QUADS) {
        float4 v = x[idx];
        ushort4 o;
        o.x = f2bf(v.x); o.y = f2bf(v.y); o.z = f2bf(v.z); o.w = f2bf(v.w);
        xn[idx] = o;
    } else if (idx < XN_QUADS + W1_ELEMS) {
        int j = idx - XN_QUADS;
        int n = j >> 9;          // / IN_DIM
        int k = j & (IN_DIM - 1);
        w1t[j] = f2bf(W1[k * HD1 + n]);
    } else if (idx < XN_QUADS + W1_ELEMS + W2_ELEMS) {
        int j = idx - XN_QUADS - W1_ELEMS;
        int n = j >> 8;          // / HD1
        int k = j & (HD1 - 1);
        w2t[j] = f2bf(W2[k * HD2 + n]);
    }
}

// ---------------- bf16 MFMA GEMM:  C[M][N] = A[M][K] * B[N][K]^T ----------------
// 128x128 tile, 4 waves (2x2) of 64x64, direct global fragment loads.
// EPI=1: logits (symmetric!): store sigmoid as transposed float4 (coalesced).
// EPI=2: v *= rownorm[row], store bf16.
// EPI=3: store bf16.
template <int EPI>
__global__ __launch_bounds__(256) void gemm_tn(const short* __restrict__ A,
                                               const short* __restrict__ B,
                                               void* __restrict__ Cv,
                                               const float* __restrict__ rownorm,
                                               int N, int K) {
    int wave = threadIdx.x >> 6;
    int lane = threadIdx.x & 63;
    int wr = wave >> 1, wc = wave & 1;
    int row0 = blockIdx.y * 128 + wr * 64;
    int col0 = blockIdx.x * 128 + wc * 64;
    int l15 = lane & 15, q = lane >> 4;

    f32x4 acc[4][4] = {};
    const short* Abase = A + (size_t)(row0 + l15) * K + q * 8;
    const short* Bbase = B + (size_t)(col0 + l15) * K + q * 8;
    int nk = K >> 5;
    for (int ks = 0; ks < nk; ks++) {
        bf16x8 a[4], b[4];
#pragma unroll
        for (int t = 0; t < 4; t++) {
            a[t] = *(const bf16x8*)(Abase + (size_t)t * 16 * K + ks * 32);
            b[t] = *(const bf16x8*)(Bbase + (size_t)t * 16 * K + ks * 32);
        }
#pragma unroll
        for (int ti = 0; ti < 4; ti++)
#pragma unroll
            for (int tj = 0; tj < 4; tj++)
                acc[ti][tj] = __builtin_amdgcn_mfma_f32_16x16x32_bf16(a[ti], b[tj], acc[ti][tj], 0, 0, 0);
    }

    if (EPI == 1) {
        // acc[ti][tj][r] = C[row0+ti*16+q*4+r][col0+tj*16+l15]; C symmetric ->
        // store at [col0+tj*16+l15][row0+ti*16+q*4 .. +3] as one float4.
        float* C = (float*)Cv;
#pragma unroll
        for (int ti = 0; ti < 4; ti++) {
#pragma unroll
            for (int tj = 0; tj < 4; tj++) {
                int row = col0 + tj * 16 + l15;
                int colb = row0 + ti * 16 + q * 4;
                float4 v;
                float* vp = (float*)&v;
#pragma unroll
                for (int r = 0; r < 4; r++) {
                    float x = acc[ti][tj][r];
                    vp[r] = __builtin_amdgcn_rcpf(1.0f + __expf(-x));
                }
                *(float4*)(C + (size_t)row * N + colb) = v;
            }
        }
    } else {
        unsigned short* C = (unsigned short*)Cv;
#pragma unroll
        for (int ti = 0; ti < 4; ti++) {
#pragma unroll
            for (int tj = 0; tj < 4; tj++) {
#pragma unroll
                for (int r = 0; r < 4; r++) {
                    int row = row0 + ti * 16 + q * 4 + r;
                    int col = col0 + tj * 16 + l15;
                    float v = acc[ti][tj][r];
                    if (EPI == 2) v *= rownorm[row];
                    C[(size_t)row * N + col] = f2bf(v);
                }
            }
        }
    }
}

// ---------------- SpMM (gather by CSR), wave-per-row ----------------

// x1n[r][f] = bf16( relu( (sum_{s in N(r)} h1b[s][f]) * nd[r] + b1[f] ) * ns[r] )
__global__ void spmm1_kernel(const ushort4* __restrict__ h1b, const int* __restrict__ row_start,
                             const int* __restrict__ eidx, const float* __restrict__ norm_dst,
                             const float* __restrict__ norm_src, const float4* __restrict__ b1,
                             ushort4* __restrict__ x1n) {
    int lane = threadIdx.x & 63;
    int r = blockIdx.x * 4 + (threadIdx.x >> 6);
    int s = row_start[r], e = row_start[r + 1];
    float sx = 0.f, sy = 0.f, sz = 0.f, sw = 0.f;
    int i = s;
    for (; i + 2 <= e; i += 2) {
        int n0 = eidx[i], n1 = eidx[i + 1];
        ushort4 v0 = h1b[n0 * 64 + lane];
        ushort4 v1 = h1b[n1 * 64 + lane];
        sx += bf2f(v0.x) + bf2f(v1.x);
        sy += bf2f(v0.y) + bf2f(v1.y);
        sz += bf2f(v0.z) + bf2f(v1.z);
        sw += bf2f(v0.w) + bf2f(v1.w);
    }
    if (i < e) {
        ushort4 v0 = h1b[eidx[i] * 64 + lane];
        sx += bf2f(v0.x); sy += bf2f(v0.y); sz += bf2f(v0.z); sw += bf2f(v0.w);
    }
    float nd = norm_dst[r], ns = norm_src[r];
    float4 bb = b1[lane];
    ushort4 o;
    o.x = f2bf(fmaxf(sx * nd + bb.x, 0.f) * ns);
    o.y = f2bf(fmaxf(sy * nd + bb.y, 0.f) * ns);
    o.z = f2bf(fmaxf(sz * nd + bb.z, 0.f) * ns);
    o.w = f2bf(fmaxf(sw * nd + bb.w, 0.f) * ns);
    x1n[r * 64 + lane] = o;
}

// emb[r][f] = sum * nd[r] + b2[f]; fp32 to d_out, bf16 for decoder
__global__ void spmm2_kernel(const ushort2* __restrict__ h2b, const int* __restrict__ row_start,
                             const int* __restrict__ eidx, const float* __restrict__ norm_dst,
                             const float2* __restrict__ b2, float2* __restrict__ emb,
                             ushort2* __restrict__ embb) {
    int lane = threadIdx.x & 63;
    int r = blockIdx.x * 4 + (threadIdx.x >> 6);
    int s = row_start[r], e = row_start[r + 1];
    float sx = 0.f, sy = 0.f;
    int i = s;
    for (; i + 2 <= e; i += 2) {
        int n0 = eidx[i], n1 = eidx[i + 1];
        ushort2 v0 = h2b[n0 * 64 + lane];
        ushort2 v1 = h2b[n1 * 64 + lane];
        sx += bf2f(v0.x) + bf2f(v1.x);
        sy += bf2f(v0.y) + bf2f(v1.y);
    }
    if (i < e) {
        ushort2 v0 = h2b[eidx[i] * 64 + lane];
        sx += bf2f(v0.x); sy += bf2f(v0.y);
    }
    float nd = norm_dst[r];
    float2 bb = b2[lane];
    float x0 = sx * nd + bb.x;
    float x1 = sy * nd + bb.y;
    float2 eo; eo.x = x0; eo.y = x1;
    emb[r * 64 + lane] = eo;
    ushort2 bo; bo.x = f2bf(x0); bo.y = f2bf(x1);
    embb[r * 64 + lane] = bo;
}

// ---------------- launch ----------------

extern "C" void kernel_launch(void* const* d_in, const int* in_sizes, int n_in,
                              void* d_out, int out_size, void* d_ws, size_t ws_size,
                              hipStream_t stream) {
    const float* features = (const float*)d_in[0];
    const int* src = (const int*)d_in[1];
    const int* dst = (const int*)d_in[2];
    const float* W1 = (const float*)d_in[3];
    const float* b1 = (const float*)d_in[4];
    const float* W2 = (const float*)d_in[5];
    const float* b2 = (const float*)d_in[6];

    char* ws = (char*)d_ws;
    size_t o = 0;
    auto alloc = [&](size_t bytes) -> char* {
        char* p = ws + o;
        o = (o + bytes + 255) & ~(size_t)255;
        return p;
    };
    int* deg_out = (int*)alloc(NN * 4);
    int* deg_in  = (int*)alloc(NN * 4);
    int* cursor  = (int*)alloc(NN * 4);   // contiguous with deg_* for one memset
    float* norm_src = (float*)alloc(NN * 4);
    float* norm_dst = (float*)alloc(NN * 4);
    int* row_start  = (int*)alloc((NN + 1) * 4);
    int* eidx       = (int*)alloc(EE * 4);
    unsigned short* xn  = (unsigned short*)alloc((size_t)NN * IN_DIM * 2);
    unsigned short* w1t = (unsigned short*)alloc((size_t)HD1 * IN_DIM * 2);
    unsigned short* w2t = (unsigned short*)alloc((size_t)HD2 * HD1 * 2);
    unsigned short* h1b = (unsigned short*)alloc((size_t)NN * HD1 * 2);
    unsigned short* x1n = (unsigned short*)alloc((size_t)NN * HD1 * 2);
    unsigned short* h2b = (unsigned short*)alloc((size_t)NN * HD2 * 2);
    unsigned short* embb = (unsigned short*)alloc((size_t)NN * HD2 * 2);

    float* emb_out = (float*)d_out;
    float* logits_out = emb_out + (size_t)NN * HD2;

    hipMemsetAsync(deg_out, 0, (size_t)NN * 4 * 3, stream);

    cast_all_kernel<<<(XN_QUADS + W1_ELEMS + W2_ELEMS) / 256, 256, 0, stream>>>(
        (const float4*)features, (ushort4*)xn, W1, w1t, W2, w2t);
    deg_kernel<<<EE / 256, 256, 0, stream>>>(src, dst, deg_out, deg_in);
    scan_norm_kernel<<<1, 256, 0, stream>>>(deg_in, deg_out, row_start, norm_src, norm_dst);
    fill_kernel<<<EE / 256, 256, 0, stream>>>(src, dst, row_start, cursor, eidx);

    // layer 1: h1b = bf16( rownorm .* (xn @ W1) )
    gemm_tn<2><<<dim3(HD1 / 128, NN / 128), 256, 0, stream>>>(
        (const short*)xn, (const short*)w1t, h1b, norm_src, HD1, IN_DIM);
    spmm1_kernel<<<NN / 4, 256, 0, stream>>>((const ushort4*)h1b, row_start, eidx,
                                             norm_dst, norm_src, (const float4*)b1,
                                             (ushort4*)x1n);

    // layer 2: h2b = bf16( x1n @ W2 )
    gemm_tn<3><<<dim3(HD2 / 128, NN / 128), 256, 0, stream>>>(
        (const short*)x1n, (const short*)w2t, h2b, nullptr, HD2, HD1);
    spmm2_kernel<<<NN / 4, 256, 0, stream>>>((const ushort2*)h2b, row_start, eidx,
                                             norm_dst, (const float2*)b2,
                                             (float2*)emb_out, (ushort2*)embb);

    // decoder: logits = sigmoid(emb @ emb^T), symmetric coalesced store
    gemm_tn<1><<<dim3(NN / 128, NN / 128), 256, 0, stream>>>(
        (const short*)embb, (const short*)embb, logits_out, nullptr, NN, HD2);
}